// Round 2
// baseline (497.224 us; speedup 1.0000x reference)
//
#include <hip/hip_runtime.h>

#define Bn 8
#define Ln 2048
#define Pn 576
#define Vn 32000
#define Dn 2560
#define Tn (Ln - 1 + Pn)          // 2623
#define IGNORE_INDEX (-100)
#define BLK 320                   // 5 waves; 6 blocks/CU = 30 waves (full occ)
#define GRIDX 192                 // 192*8 = 1536 blocks = 6 per CU

// Persistent-ish blocks: each block owns batch b = blockIdx.y and loops over
// rows t with stride GRIDX. Software-pipelined: row k's stores wait only on
// row k's loads while row k+1's id + row loads are already in flight.
__global__ __launch_bounds__(BLK) void splice_kernel(
    const float* __restrict__ embed_table,     // (V, D)
    const float* __restrict__ image_features,  // (B, P, D)
    const int*   __restrict__ input_ids,       // (B, L)
    const int*   __restrict__ labels,          // (B, L)
    const int*   __restrict__ img_pos,         // (B,)
    float* __restrict__ out)                   // embeds | labels | mask | pos
{
    const int b   = blockIdx.y;
    const int tid = threadIdx.x;
    const int pos = img_pos[b];                 // hoisted: 1 load per block

    const int* __restrict__ ids_row = input_ids + b * Ln;
    const int* __restrict__ lab_row = labels    + b * Ln;

    const size_t nBT  = (size_t)Bn * Tn;
    float* __restrict__ outL = out + nBT * (size_t)Dn;  // new_labels
    float* __restrict__ outM = outL + nBT;              // attention_mask
    float* __restrict__ outP = outM + nBT;              // position_ids

    // Source row pointer + label for output row t (uniform across block).
    auto src_of = [&](int t, int& lab) -> const float4* {
        if (t >= pos && t < pos + Pn) {
            lab = IGNORE_INDEX;
            return (const float4*)(image_features +
                                   ((size_t)b * Pn + (t - pos)) * Dn);
        }
        int tok = (t < pos) ? t : (t - Pn + 1);
        tok = min(max(tok, 0), Ln - 1);
        lab = lab_row[tok];
        const int id = ids_row[tok];
        return (const float4*)(embed_table + (size_t)id * Dn);
    };

    int t = blockIdx.x;                          // GRIDX < Tn, always valid
    int lab_c;
    const float4* src_c = src_of(t, lab_c);
    float4 a0 = src_c[tid];
    float4 a1 = src_c[tid + BLK];

    while (t < Tn) {
        const int tn = t + GRIDX;

        // ---- prefetch next row (id chain + row data) ----
        int lab_n = 0;
        const float4* src_n = src_c;
        if (tn < Tn) src_n = src_of(tn, lab_n);
        float4 b0 = src_n[tid];                  // in flight during stores
        float4 b1 = src_n[tid + BLK];

        // ---- store current row (waits only on a0/a1) ----
        float4* __restrict__ dst =
            (float4*)(out + ((size_t)b * Tn + t) * Dn);
        dst[tid]       = a0;
        dst[tid + BLK] = a1;

        if (tid == 0) {
            const size_t idx = (size_t)b * Tn + t;
            outL[idx] = (float)lab_c;
            outM[idx] = 1.0f;
            outP[idx] = (float)t;
        }

        a0 = b0; a1 = b1; lab_c = lab_n; src_c = src_n;
        t = tn;
    }
}

extern "C" void kernel_launch(void* const* d_in, const int* in_sizes, int n_in,
                              void* d_out, int out_size, void* d_ws, size_t ws_size,
                              hipStream_t stream) {
    const float* embed_table    = (const float*)d_in[0];
    const float* image_features = (const float*)d_in[1];
    const int*   input_ids      = (const int*)d_in[2];
    const int*   labels         = (const int*)d_in[3];
    const int*   img_pos        = (const int*)d_in[4];
    float* out = (float*)d_out;

    dim3 grid(GRIDX, Bn);
    dim3 block(BLK);
    splice_kernel<<<grid, block, 0, stream>>>(embed_table, image_features,
                                              input_ids, labels, img_pos, out);
}